// Round 3
// baseline (5092.213 us; speedup 1.0000x reference)
//
#include <hip/hip_runtime.h>
#include <math.h>

// ---------------------------------------------------------------------------
// CondConv AlexNet, fp32 direct implementation.
// B=128. Layers:
//  conv1: 3->64,   224x224 -> 55x55, k11 s4 p2
//  pool1: 55->27
//  conv2: 64->192, 27x27, k5 s1 p2
//  pool2: 27->13
//  conv3: 192->384, 13x13, k3 s1 p1
//  conv4: 384->256
//  conv5: 256->256
//  pool5: 13->6 ; flatten 9216
//  fc1 9216->4096 relu, fc2 4096->4096 relu, fc3 4096->1000
// ---------------------------------------------------------------------------

#ifndef NEXPERT
#define NEXPERT 8
#endif

// ---------------- global average pool (per (b,c) plane) ----------------
__global__ __launch_bounds__(256) void gap_kernel(const float* __restrict__ in,
                                                  float* __restrict__ out,
                                                  int HW, float inv) {
  const int bc = blockIdx.x;
  const float* p = in + (size_t)bc * HW;
  float s = 0.f;
  for (int i = threadIdx.x; i < HW; i += 256) s += p[i];
#pragma unroll
  for (int off = 32; off > 0; off >>= 1) s += __shfl_down(s, off, 64);
  __shared__ float red[4];
  if ((threadIdx.x & 63) == 0) red[threadIdx.x >> 6] = s;
  __syncthreads();
  if (threadIdx.x == 0) out[bc] = (red[0] + red[1] + red[2] + red[3]) * inv;
}

// ---------------- routing: r = sigmoid(pooled@rw+rb); bb = r@bias ------
__global__ __launch_bounds__(64) void route_kernel(const float* __restrict__ pooled,
                                                   const float* __restrict__ rw,
                                                   const float* __restrict__ rb,
                                                   const float* __restrict__ bias,
                                                   float* __restrict__ rout,
                                                   float* __restrict__ bb,
                                                   int CIN, int COUT) {
  const int b = blockIdx.x;
  __shared__ float rs[NEXPERT];
  const int t = threadIdx.x;
  if (t < NEXPERT) {
    float z = rb[t];
    const float* pb = pooled + (size_t)b * CIN;
    for (int ci = 0; ci < CIN; ++ci) z += pb[ci] * rw[ci * NEXPERT + t];
    float rv = 1.f / (1.f + expf(-z));
    rs[t] = rv;
    rout[b * NEXPERT + t] = rv;
  }
  __syncthreads();
  for (int co = t; co < COUT; co += 64) {
    float s = 0.f;
#pragma unroll
    for (int k = 0; k < NEXPERT; ++k) s += rs[k] * bias[k * COUT + co];
    bb[(size_t)b * COUT + co] = s;
  }
}

// ---------------- max pool 3x3 stride 2 ----------------
__global__ __launch_bounds__(256) void maxpool_kernel(const float* __restrict__ in,
                                                      float* __restrict__ out,
                                                      int total, int C, int HI, int WI,
                                                      int HO, int WO) {
  int idx = blockIdx.x * 256 + threadIdx.x;
  if (idx >= total) return;
  int ow = idx % WO;
  int t = idx / WO;
  int oh = t % HO;
  t /= HO;
  int c = t % C;
  int b = t / C;
  const float* p = in + ((size_t)(b * C + c) * HI + oh * 2) * WI + ow * 2;
  float m = -INFINITY;
#pragma unroll
  for (int i = 0; i < 3; ++i)
#pragma unroll
    for (int j = 0; j < 3; ++j) {
      float v = p[i * WI + j];
      m = v > m ? v : m;
    }
  out[idx] = m;
}

// ---------------- CondConv direct conv -------------------------------------
// Block: (b, cout-tile cob, row-tile). 256 threads = 4 co-groups x 64 px slots.
// Per cin-chunk: stage input tile + expert-mixed weights into LDS, accumulate.
// Weight LDS layout [ci][kk][co] stride COTP (pad for b128-aligned reads).
template <int CIN, int COUT, int HIN, int WIN, int HOUT, int WOUT, int KS, int STR,
          int PAD, int COT, int CPT, int CIC, int ROWS, int NP, bool SWZ>
__global__ __launch_bounds__(256) void condconv_kernel(const float* __restrict__ in,
                                                       const float* __restrict__ w,
                                                       const float* __restrict__ rbuf,
                                                       const float* __restrict__ bbuf,
                                                       float* __restrict__ out) {
  constexpr int KS2 = KS * KS;
  constexpr int TR = (ROWS - 1) * STR + KS;
  constexpr int TW = (WOUT - 1) * STR + KS;
  constexpr int TWP = TW + 1;
  constexpr int COTP = (COT == 64) ? 68 : 36;  // pad: keeps cog*CPT 16B aligned
  static_assert(COT / CPT == 4, "need 4 co-groups");
  static_assert(NP * 64 >= ROWS * WOUT, "NP too small");
  static_assert((CPT % 4) == 0 && (COTP % 4) == 0, "b128 alignment");

  extern __shared__ float lds[];
  float* lds_in = lds;                      // CIC*TR*TWP
  float* lds_w = lds + CIC * TR * TWP;      // CIC*KS2*COTP

  const int tid = threadIdx.x;
  const int slot = tid & 63;
  const int cog = tid >> 6;
  const int b = blockIdx.x;
  const int cob = blockIdx.y;
  const int oh0 = blockIdx.z * ROWS;
  const int rows_here = min(ROWS, HOUT - oh0);
  const int npix = rows_here * WOUT;
  const int co0 = cob * COT + cog * CPT;

  float rk[NEXPERT];
#pragma unroll
  for (int k = 0; k < NEXPERT; ++k) rk[k] = rbuf[b * NEXPERT + k];

  int lrj[NP], owj[NP];
#pragma unroll
  for (int j = 0; j < NP; ++j) {
    int p = slot + j * 64;
    if (p > npix - 1) p = npix - 1;  // clamp; masked at store
    lrj[j] = p / WOUT;
    owj[j] = p % WOUT;
  }

  float acc[CPT][NP];
#pragma unroll
  for (int i = 0; i < CPT; ++i)
#pragma unroll
    for (int j = 0; j < NP; ++j) acc[i][j] = 0.f;

  constexpr int NCHUNK = CIN / CIC;
  static_assert(NCHUNK * CIC == CIN, "CIC must divide CIN");

  for (int ch = 0; ch < NCHUNK; ++ch) {
    const int ci0 = ch * CIC;
    __syncthreads();
    // ---- stage input tile (with zero pad + optional xor swizzle) ----
    {
      constexpr int TOT = CIC * TR * TW;
      for (int idx = tid; idx < TOT; idx += 256) {
        int ci = idx / (TR * TW);
        int rem = idx - ci * (TR * TW);
        int tr = rem / TW;
        int tc = rem - tr * TW;
        int gr = oh0 * STR - PAD + tr;
        int gc = tc - PAD;
        float v = 0.f;
        if (gr >= 0 && gr < HIN && gc >= 0 && gc < WIN)
          v = in[((size_t)(b * CIN + ci0 + ci) * HIN + gr) * WIN + gc];
        int tcs = SWZ ? (tc ^ ((tc >> 5) & 3)) : tc;
        lds_in[(ci * TR + tr) * TWP + tcs] = v;
      }
    }
    // ---- stage expert-mixed weights ----
    {
      constexpr int TOT = CIC * KS2 * COT;
      constexpr size_t ESTR = (size_t)COUT * CIN * KS2;  // expert stride
      for (int idx = tid; idx < TOT; idx += 256) {
        int co = idx / (CIC * KS2);
        int rem = idx - co * (CIC * KS2);
        int ci = rem / KS2;
        int kk = rem - ci * KS2;
        const float* wp =
            w + ((size_t)(cob * COT + co) * CIN + ci0 + ci) * KS2 + kk;
        float s = 0.f;
#pragma unroll
        for (int k = 0; k < NEXPERT; ++k) s += rk[k] * wp[k * ESTR];
        lds_w[(ci * KS2 + kk) * COTP + co] = s;
      }
    }
    __syncthreads();
    // ---- compute ----
#pragma unroll 1
    for (int ci = 0; ci < CIC; ++ci) {
#pragma unroll 1
      for (int kh = 0; kh < KS; ++kh) {
#pragma unroll
        for (int kw = 0; kw < KS; ++kw) {
          const float4* wp4 = reinterpret_cast<const float4*>(
              &lds_w[(ci * KS2 + kh * KS + kw) * COTP + cog * CPT]);
          float4 wq[CPT / 4];
#pragma unroll
          for (int q = 0; q < CPT / 4; ++q) wq[q] = wp4[q];
#pragma unroll
          for (int j = 0; j < NP; ++j) {
            int col = owj[j] * STR + kw;
            if (SWZ) col = col ^ ((col >> 5) & 3);
            float iv = lds_in[(ci * TR + lrj[j] * STR + kh) * TWP + col];
#pragma unroll
            for (int q = 0; q < CPT / 4; ++q) {
              acc[q * 4 + 0][j] += wq[q].x * iv;
              acc[q * 4 + 1][j] += wq[q].y * iv;
              acc[q * 4 + 2][j] += wq[q].z * iv;
              acc[q * 4 + 3][j] += wq[q].w * iv;
            }
          }
        }
      }
    }
  }
  // ---- epilogue: +bias, relu, store ----
  float bbv[CPT];
#pragma unroll
  for (int i = 0; i < CPT; ++i) bbv[i] = bbuf[(size_t)b * COUT + co0 + i];
#pragma unroll
  for (int j = 0; j < NP; ++j) {
    int p = slot + j * 64;
    if (p < npix) {
      int oh = oh0 + lrj[j], ow = owj[j];
#pragma unroll
      for (int i = 0; i < CPT; ++i) {
        float v = acc[i][j] + bbv[i];
        out[((size_t)(b * COUT + co0 + i) * HOUT + oh) * WOUT + ow] =
            v > 0.f ? v : 0.f;
      }
    }
  }
}

// ---------------- FC: out[m][n] = bias[n] init ----------------
__global__ __launch_bounds__(256) void bias_init_kernel(float* __restrict__ out,
                                                        const float* __restrict__ bias,
                                                        int total, int N) {
  int idx = blockIdx.x * 256 + threadIdx.x;
  if (idx < total) out[idx] = bias[idx % N];
}

__global__ __launch_bounds__(256) void relu_kernel(float* __restrict__ x, int total) {
  int idx = blockIdx.x * 256 + threadIdx.x;
  if (idx < total) {
    float v = x[idx];
    x[idx] = v > 0.f ? v : 0.f;
  }
}

// ---------------- FC GEMM, split-K with atomic accumulate ----------------
// A [128][K] row-major, W [K][N] row-major. BM=128 BN=64 BK=32.
__global__ __launch_bounds__(256) void fc_gemm_kernel(const float* __restrict__ A,
                                                      const float* __restrict__ W,
                                                      float* __restrict__ out, int N,
                                                      int K, int kspan) {
  constexpr int BM = 128, BN = 64, BK = 32, BMP = 132, BNP = 68;
  __shared__ float sa[BK * BMP];
  __shared__ float sb[BK * BNP];
  const int tid = threadIdx.x;
  const int tn = tid & 15, tm = tid >> 4;
  const int n0 = blockIdx.x * BN;
  const int k0 = blockIdx.y * kspan;
  const int k1 = k0 + kspan;
  float acc[8][4];
#pragma unroll
  for (int i = 0; i < 8; ++i)
#pragma unroll
    for (int j = 0; j < 4; ++j) acc[i][j] = 0.f;

  for (int kt = k0; kt < k1; kt += BK) {
    __syncthreads();
    for (int idx = tid; idx < BM * BK; idx += 256) {
      int m = idx >> 5, kk = idx & 31;
      sa[kk * BMP + m] = A[(size_t)m * K + kt + kk];
    }
    for (int idx = tid; idx < BK * BN; idx += 256) {
      int kk = idx >> 6, n = idx & 63;
      int nn = n0 + n;
      sb[kk * BNP + n] = (nn < N) ? W[(size_t)(kt + kk) * N + nn] : 0.f;
    }
    __syncthreads();
#pragma unroll
    for (int kk = 0; kk < BK; ++kk) {
      float4 a0 = *reinterpret_cast<const float4*>(&sa[kk * BMP + tm * 8]);
      float4 a1 = *reinterpret_cast<const float4*>(&sa[kk * BMP + tm * 8 + 4]);
      float4 bq = *reinterpret_cast<const float4*>(&sb[kk * BNP + tn * 4]);
      float av[8] = {a0.x, a0.y, a0.z, a0.w, a1.x, a1.y, a1.z, a1.w};
#pragma unroll
      for (int i = 0; i < 8; ++i) {
        acc[i][0] += av[i] * bq.x;
        acc[i][1] += av[i] * bq.y;
        acc[i][2] += av[i] * bq.z;
        acc[i][3] += av[i] * bq.w;
      }
    }
  }
#pragma unroll
  for (int i = 0; i < 8; ++i) {
    int m = tm * 8 + i;
#pragma unroll
    for (int j = 0; j < 4; ++j) {
      int nn = n0 + tn * 4 + j;
      if (nn < N) atomicAdd(&out[(size_t)m * N + nn], acc[i][j]);
    }
  }
}

// ---------------------------------------------------------------------------
extern "C" void kernel_launch(void* const* d_in, const int* in_sizes, int n_in,
                              void* d_out, int out_size, void* d_ws, size_t ws_size,
                              hipStream_t stream) {
  (void)in_sizes;
  (void)n_in;
  (void)ws_size;
  (void)out_size;

  const float* x = (const float*)d_in[0];
  const float* w1 = (const float*)d_in[1];
  const float* b1 = (const float*)d_in[2];
  const float* rw1 = (const float*)d_in[3];
  const float* rb1 = (const float*)d_in[4];
  const float* w2 = (const float*)d_in[5];
  const float* b2 = (const float*)d_in[6];
  const float* rw2 = (const float*)d_in[7];
  const float* rb2 = (const float*)d_in[8];
  const float* w3 = (const float*)d_in[9];
  const float* b3 = (const float*)d_in[10];
  const float* rw3 = (const float*)d_in[11];
  const float* rb3 = (const float*)d_in[12];
  const float* w4 = (const float*)d_in[13];
  const float* b4 = (const float*)d_in[14];
  const float* rw4 = (const float*)d_in[15];
  const float* rb4 = (const float*)d_in[16];
  const float* w5 = (const float*)d_in[17];
  const float* b5 = (const float*)d_in[18];
  const float* rw5 = (const float*)d_in[19];
  const float* rb5 = (const float*)d_in[20];
  const float* fw1 = (const float*)d_in[21];
  const float* fb1 = (const float*)d_in[22];
  const float* fw2 = (const float*)d_in[23];
  const float* fb2 = (const float*)d_in[24];
  const float* fw3 = (const float*)d_in[25];
  const float* fb3 = (const float*)d_in[26];
  float* outp = (float*)d_out;

  float* ws = (float*)d_ws;
  // workspace layout (floats); aliasing is deliberate (lifetimes disjoint).
  // NOTE: pooled/rbuf/bbuf live ABOVE every activation region — conv kernels
  // read rbuf/bbuf while writing their act output (r1 bug: they overlapped act1).
  float* act1 = ws + 0;          // 24,780,800  [128,64,55,55]
  float* p1 = ws + 25000000;     //  5,971,968  [128,64,27,27]
  float* act2 = ws + 0;          // 17,915,904  [128,192,27,27]
  float* p2 = ws + 31000000;     //  4,153,344  [128,192,13,13]  ends 35,153,344
  float* act3 = ws + 0;          //  8,306,688  [128,384,13,13]
  float* act4 = ws + 9000000;    //  5,537,792  [128,256,13,13]
  float* act5 = ws + 0;          //  5,537,792  [128,256,13,13]
  float* p5 = ws + 15000000;     //  1,179,648  [128,9216]
  float* F1 = ws + 17000000;     //    524,288  [128,4096]
  float* F2 = ws + 18000000;     //    524,288  [128,4096]
  float* pooled = ws + 35200000; //  <= 49,152  [128, Cin]
  float* rbuf = ws + 35250000;   //      1,024  [128,8]
  float* bbuf = ws + 35260000;   //  <= 49,152  [128, Cout]   ends 35,309,152

  const int B = 128;

  // ---------------- layer 1 ----------------
  gap_kernel<<<B * 3, 256, 0, stream>>>(x, pooled, 224 * 224, 1.f / (224.f * 224.f));
  route_kernel<<<B, 64, 0, stream>>>(pooled, rw1, rb1, b1, rbuf, bbuf, 3, 64);
  // conv1: COT=32 CPT=8 CIC=1 (3 chunks) ROWS=5 NP=5 swizzled; LDS 42 KB
  condconv_kernel<3, 64, 224, 224, 55, 55, 11, 4, 2, 32, 8, 1, 5, 5, true>
      <<<dim3(B, 2, 11), 256, (1 * 27 * 228 + 1 * 121 * 36) * 4, stream>>>(
          x, w1, rbuf, bbuf, act1);
  {
    int total = B * 64 * 27 * 27;
    maxpool_kernel<<<(total + 255) / 256, 256, 0, stream>>>(act1, p1, total, 64, 55,
                                                            55, 27, 27);
  }

  // ---------------- layer 2 ----------------
  gap_kernel<<<B * 64, 256, 0, stream>>>(p1, pooled, 27 * 27, 1.f / 729.f);
  route_kernel<<<B, 64, 0, stream>>>(pooled, rw2, rb2, b2, rbuf, bbuf, 64, 192);
  condconv_kernel<64, 192, 27, 27, 27, 27, 5, 1, 2, 32, 8, 8, 14, 6, false>
      <<<dim3(B, 6, 2), 256, (8 * 18 * 32 + 8 * 25 * 36) * 4, stream>>>(
          p1, w2, rbuf, bbuf, act2);
  {
    int total = B * 192 * 13 * 13;
    maxpool_kernel<<<(total + 255) / 256, 256, 0, stream>>>(act2, p2, total, 192, 27,
                                                            27, 13, 13);
  }

  // ---------------- layer 3 ----------------
  gap_kernel<<<B * 192, 256, 0, stream>>>(p2, pooled, 13 * 13, 1.f / 169.f);
  route_kernel<<<B, 64, 0, stream>>>(pooled, rw3, rb3, b3, rbuf, bbuf, 192, 384);
  condconv_kernel<192, 384, 13, 13, 13, 13, 3, 1, 1, 64, 16, 16, 13, 3, false>
      <<<dim3(B, 6, 1), 256, (16 * 15 * 16 + 16 * 9 * 68) * 4, stream>>>(
          p2, w3, rbuf, bbuf, act3);

  // ---------------- layer 4 ----------------
  gap_kernel<<<B * 384, 256, 0, stream>>>(act3, pooled, 13 * 13, 1.f / 169.f);
  route_kernel<<<B, 64, 0, stream>>>(pooled, rw4, rb4, b4, rbuf, bbuf, 384, 256);
  condconv_kernel<384, 256, 13, 13, 13, 13, 3, 1, 1, 64, 16, 16, 13, 3, false>
      <<<dim3(B, 4, 1), 256, (16 * 15 * 16 + 16 * 9 * 68) * 4, stream>>>(
          act3, w4, rbuf, bbuf, act4);

  // ---------------- layer 5 ----------------
  gap_kernel<<<B * 256, 256, 0, stream>>>(act4, pooled, 13 * 13, 1.f / 169.f);
  route_kernel<<<B, 64, 0, stream>>>(pooled, rw5, rb5, b5, rbuf, bbuf, 256, 256);
  condconv_kernel<256, 256, 13, 13, 13, 13, 3, 1, 1, 64, 16, 16, 13, 3, false>
      <<<dim3(B, 4, 1), 256, (16 * 15 * 16 + 16 * 9 * 68) * 4, stream>>>(
          act4, w5, rbuf, bbuf, act5);
  {
    int total = B * 256 * 6 * 6;
    maxpool_kernel<<<(total + 255) / 256, 256, 0, stream>>>(act5, p5, total, 256, 13,
                                                            13, 6, 6);
  }

  // ---------------- FC ----------------
  {
    int total = B * 4096;
    bias_init_kernel<<<(total + 255) / 256, 256, 0, stream>>>(F1, fb1, total, 4096);
    fc_gemm_kernel<<<dim3(64, 4), 256, 0, stream>>>(p5, fw1, F1, 4096, 9216, 2304);
    relu_kernel<<<(total + 255) / 256, 256, 0, stream>>>(F1, total);

    bias_init_kernel<<<(total + 255) / 256, 256, 0, stream>>>(F2, fb2, total, 4096);
    fc_gemm_kernel<<<dim3(64, 4), 256, 0, stream>>>(F1, fw2, F2, 4096, 4096, 1024);
    relu_kernel<<<(total + 255) / 256, 256, 0, stream>>>(F2, total);

    int total3 = B * 1000;
    bias_init_kernel<<<(total3 + 255) / 256, 256, 0, stream>>>(outp, fb3, total3,
                                                               1000);
    fc_gemm_kernel<<<dim3(16, 16), 256, 0, stream>>>(F2, fw3, outp, 1000, 4096, 256);
  }
}